// Round 7
// baseline (59.768 us; speedup 1.0000x reference)
//
#include <hip/hip_runtime.h>

#define MM      32768
#define TPB     256
#define TILE    4096                // bins per tile
#define NTILE   16
#define CHUNK   256                 // i-limbs per chunk
#define NPAIRS  576                 // (tile, chunk-pair) work units
#define NPACK   (MM / 2 + 1)        // 16385 packed B entries
#define EPAD    2304                // staged E dwords (9 * 256)
#define APAD    144
#define PA_OFS  0
#define PE_OFS  16384
#define CTR_OFS 32800               // queue counter (dword index)
#define P_OFS   33024               // partials base (dword index)
#define GRID    512                 // 2 blocks / CU, persistent

typedef unsigned short ushort2e __attribute__((ext_vector_type(2)));

// 2 exact u16 MACs mod 2^32 (u32 wrap == the int32 the harness compares).
__device__ __forceinline__ unsigned DOT2(unsigned a, unsigned b, unsigned c) {
#if __has_builtin(__builtin_amdgcn_udot2)
    return __builtin_amdgcn_udot2(__builtin_bit_cast(ushort2e, a),
                                  __builtin_bit_cast(ushort2e, b), c, false);
#else
    return c + (a & 0xFFFFu) * (b & 0xFFFFu) + (a >> 16) * (b >> 16);
#endif
}

// O[n] = (E[n]<<16) | (E[n+1]>>16)  — edge-safe given E's zero-pad rules.
__device__ __forceinline__ unsigned ALN(unsigned hi, unsigned lo) {
#if __has_builtin(__builtin_amdgcn_alignbit)
    return __builtin_amdgcn_alignbit(hi, lo, 16);
#else
    return (hi << 16) | (lo >> 16);
#endif
}

// LDS dword swizzle: XOR bits 5-6 into bank bits 3-4. Bits 0-2 untouched ->
// 16B quads stay contiguous; bijective; spreads the 32B/lane read stride
// across all banks. Writes (s = t + 256i) stay conflict-free.
__device__ __forceinline__ int swz(int s) { return s ^ ((s >> 2) & 24); }

// Pairs per tile: 8(t+1) for t<8 else 8(16-t); sum = 576.
__device__ __forceinline__ int pairs_of(int t) {
    return (t < NTILE / 2) ? 8 * (t + 1) : 8 * (NTILE - t);
}

__device__ __forceinline__ void decode_pair(int pair, int& k0, int& i0b) {
    int id = pair, tile = 0;
#pragma unroll 1
    for (; tile < NTILE - 1; ++tile) {
        const int c = pairs_of(tile);
        if (id < c) break;
        id -= c;
    }
    k0 = tile << 12;
    int iMin = k0 - (MM - 1); if (iMin < 0) iMin = 0;
    i0b = ((iMin >> 8) + 2 * id) << 8;   // first chunk's base limb
}

// PA[m]=(lo A[2m], hi A[2m+1]); PE[n]=(lo B[2n], hi B[2n-1]).
__global__ __launch_bounds__(TPB) void pack_kernel(
    const int* __restrict__ A, const int* __restrict__ B, unsigned* __restrict__ ws)
{
    const int e = (int)blockIdx.x * TPB + (int)threadIdx.x;
    if (e < MM / 2)
        ws[PA_OFS + e] = (unsigned)A[2 * e] | ((unsigned)A[2 * e + 1] << 16);
    if (e < NPACK) {
        const unsigned elo = (e < MM / 2) ? (unsigned)B[2 * e] : 0u;
        const unsigned ehi = (e >= 1) ? (unsigned)B[2 * e - 1] : 0u;
        ws[PE_OFS + e] = elo | (ehi << 16);
    }
}

struct Stg { unsigned r0, r1, r2, r3, r4, r5, r6, r7, r8, ra; };
struct Acc { unsigned ae0, ae1, ae2, ae3, ae4, ae5, ae6, ae7,
                      ao0, ao1, ao2, ao3, ao4, ao5, ao6, ao7; };

__device__ __forceinline__ void load_regs(const unsigned* __restrict__ PE,
                                          const unsigned* __restrict__ PA,
                                          int k0, int i0, int t, Stg& S)
{
    const int n0 = (k0 >> 1) - (i0 >> 1) - 127;
    const int Am0 = (i0 >> 1) + 127;
#define LD(j, dst) { const int n = n0 + t + 256 * (j);                          \
                     dst = (n >= 0 && n < NPACK) ? PE[n] : 0u; }
    LD(0, S.r0) LD(1, S.r1) LD(2, S.r2) LD(3, S.r3) LD(4, S.r4)
    LD(5, S.r5) LD(6, S.r6) LD(7, S.r7) LD(8, S.r8)
#undef LD
    S.ra = (t < 128) ? PA[Am0 - t] : 0u;
}

__device__ __forceinline__ void dsw(unsigned* eSh, unsigned* aSh, int t, const Stg& S)
{
#define ST(j, src) eSh[swz(t + 256 * (j))] = src;
    ST(0, S.r0) ST(1, S.r1) ST(2, S.r2) ST(3, S.r3) ST(4, S.r4)
    ST(5, S.r5) ST(6, S.r6) ST(7, S.r7) ST(8, S.r8)
#undef ST
    if (t < APAD) aSh[t] = S.ra;
}

// Row: 8 even + 8 odd dot2s sharing one broadcast A value.
#define STEP16(a, E0,E1,E2,E3,E4,E5,E6,E7, Q0,Q1,Q2,Q3,Q4,Q5,Q6,Q7)             \
    C.ae0 = DOT2(a, E0, C.ae0); C.ae1 = DOT2(a, E1, C.ae1);                     \
    C.ae2 = DOT2(a, E2, C.ae2); C.ae3 = DOT2(a, E3, C.ae3);                     \
    C.ae4 = DOT2(a, E4, C.ae4); C.ae5 = DOT2(a, E5, C.ae5);                     \
    C.ae6 = DOT2(a, E6, C.ae6); C.ae7 = DOT2(a, E7, C.ae7);                     \
    C.ao0 = DOT2(a, Q0, C.ao0); C.ao1 = DOT2(a, Q1, C.ao1);                     \
    C.ao2 = DOT2(a, Q2, C.ao2); C.ao3 = DOT2(a, Q3, C.ao3);                     \
    C.ao4 = DOT2(a, Q4, C.ao4); C.ao5 = DOT2(a, Q5, C.ao5);                     \
    C.ao6 = DOT2(a, Q6, C.ao6); C.ao7 = DOT2(a, Q7, C.ao7);

// Group G: quads W=G, X=G+1, Y=G+2 live; prefetch Z=G+3 (E and A).
#define GROUP16(G, W, X, Y, Z, AW, AX, AY, AZ) {                                \
    { const int q = bd + 4 * (G) + 12;                                          \
      Z = *(const uint4*)&eSh[swz(q)]; }                                        \
    AZ = *(const uint4*)&aSh[4 * (G) + 12];                                     \
    const unsigned o0 = ALN(W.x, W.y), o1 = ALN(W.y, W.z), o2 = ALN(W.z, W.w);  \
    const unsigned o3 = ALN(W.w, X.x), o4 = ALN(X.x, X.y), o5 = ALN(X.y, X.z);  \
    const unsigned o6 = ALN(X.z, X.w), o7 = ALN(X.w, Y.x), o8 = ALN(Y.x, Y.y);  \
    const unsigned o9 = ALN(Y.y, Y.z), o10 = ALN(Y.z, Y.w);                     \
    STEP16(AW.x, W.x,W.y,W.z,W.w,X.x,X.y,X.z,X.w, o0,o1,o2,o3,o4,o5,o6,o7)      \
    STEP16(AW.y, W.y,W.z,W.w,X.x,X.y,X.z,X.w,Y.x, o1,o2,o3,o4,o5,o6,o7,o8)      \
    STEP16(AW.z, W.z,W.w,X.x,X.y,X.z,X.w,Y.x,Y.y, o2,o3,o4,o5,o6,o7,o8,o9)      \
    STEP16(AW.w, W.w,X.x,X.y,X.z,X.w,Y.x,Y.y,Y.z, o3,o4,o5,o6,o7,o8,o9,o10)     \
}

__device__ __forceinline__ void compute_chunk(const unsigned* __restrict__ eSh,
                                              const unsigned* __restrict__ aSh,
                                              int t, Acc& C)
{
    const int bd = 8 * t;
    uint4 E0 = *(const uint4*)&eSh[swz(bd)];
    uint4 E1 = *(const uint4*)&eSh[swz(bd + 4)];
    uint4 E2 = *(const uint4*)&eSh[swz(bd + 8)];
    uint4 A0 = *(const uint4*)&aSh[0];
    uint4 A1 = *(const uint4*)&aSh[4];
    uint4 A2 = *(const uint4*)&aSh[8];
    uint4 E3, A3;
#pragma unroll
    for (int oi = 0; oi < 8; ++oi) {
        GROUP16(4 * oi + 0, E0, E1, E2, E3, A0, A1, A2, A3);
        GROUP16(4 * oi + 1, E1, E2, E3, E0, A1, A2, A3, A0);
        GROUP16(4 * oi + 2, E2, E3, E0, E1, A2, A3, A0, A1);
        GROUP16(4 * oi + 3, E3, E0, E1, E2, A3, A0, A1, A2);
    }
}

__device__ __forceinline__ void zero_acc(Acc& C) {
    C.ae0=C.ae1=C.ae2=C.ae3=C.ae4=C.ae5=C.ae6=C.ae7=0u;
    C.ao0=C.ao1=C.ao2=C.ao3=C.ao4=C.ao5=C.ao6=C.ao7=0u;
}

__device__ __forceinline__ void store_partial(unsigned* __restrict__ part,
                                              int pair, int t, const Acc& C)
{
    unsigned* w = part + (size_t)pair * TILE + 16 * t;
    *(uint4*)&w[0]  = make_uint4(C.ae0, C.ao0, C.ae1, C.ao1);
    *(uint4*)&w[4]  = make_uint4(C.ae2, C.ao2, C.ae3, C.ao3);
    *(uint4*)&w[8]  = make_uint4(C.ae4, C.ao4, C.ae5, C.ao5);
    *(uint4*)&w[12] = make_uint4(C.ae6, C.ao6, C.ae7, C.ao7);
}

// Persistent blocks pop (tile, chunk-pair) units from a queue; partials are
// indexed by unit id -> output is deterministic regardless of scheduling.
__global__ __launch_bounds__(TPB) void conv_kernel(
    const unsigned* __restrict__ PA, const unsigned* __restrict__ PE,
    unsigned* __restrict__ ctr, unsigned* __restrict__ part)
{
    __shared__ __align__(16) unsigned eSh[EPAD];
    __shared__ __align__(16) unsigned aSh[APAD];
    __shared__ unsigned qSh;

    const int t = (int)threadIdx.x;
    Stg S; Acc C;

    if (t == 0) qSh = atomicAdd(ctr, 1u);
    __syncthreads();
    int pairA = (int)qSh;
    if (pairA >= NPAIRS) return;

    int k0A, i0A;
    decode_pair(pairA, k0A, i0A);

    // Prologue: stage pairA chunk0; pop pairB.
    load_regs(PE, PA, k0A, i0A, t, S);
    dsw(eSh, aSh, t, S);
    if (t == 0) qSh = atomicAdd(ctr, 1u);
    __syncthreads();
    int pairB = (int)qSh;

#pragma unroll 1
    for (;;) {
        // LDS holds pairA chunk0. Issue chunk1 loads, compute chunk0.
        load_regs(PE, PA, k0A, i0A + CHUNK, t, S);
        zero_acc(C);
        compute_chunk(eSh, aSh, t, C);
        __syncthreads();
        dsw(eSh, aSh, t, S);
        __syncthreads();

        const bool haveB = (pairB < NPAIRS);
        int k0B = 0, i0B = 0;
        if (haveB) {
            decode_pair(pairB, k0B, i0B);
            load_regs(PE, PA, k0B, i0B, t, S);   // in flight under compute
        }
        compute_chunk(eSh, aSh, t, C);           // chunk1
        store_partial(part, pairA, t, C);
        if (!haveB) break;

        __syncthreads();
        dsw(eSh, aSh, t, S);                      // pairB chunk0 -> LDS
        if (t == 0) qSh = atomicAdd(ctr, 1u);
        __syncthreads();
        pairA = pairB; k0A = k0B; i0A = i0B;
        pairB = (int)qSh;
    }
}

__global__ __launch_bounds__(TPB) void reduce_kernel(
    const unsigned* __restrict__ part, unsigned* __restrict__ out)
{
    const int k = (int)blockIdx.x * TPB + (int)threadIdx.x;
    const int tile = k >> 12;

    int base = 0;
#pragma unroll 1
    for (int s = 0; s < NTILE - 1; ++s) {
        if (s >= tile) break;
        base += pairs_of(s);
    }
    const int cnt = pairs_of(tile);

    const unsigned* p = part + (size_t)base * TILE + (k & (TILE - 1));
    unsigned s0 = 0, s1 = 0, s2 = 0, s3 = 0;
    int c = 0;
#pragma unroll 1
    for (; c + 4 <= cnt; c += 4) {
        s0 += p[(size_t)(c + 0) * TILE]; s1 += p[(size_t)(c + 1) * TILE];
        s2 += p[(size_t)(c + 2) * TILE]; s3 += p[(size_t)(c + 3) * TILE];
    }
    for (; c < cnt; ++c) s0 += p[(size_t)c * TILE];
    out[k] = s0 + s1 + s2 + s3;
}

// Fallback (ws too small): one pair per block, atomic accumulate into out.
__global__ __launch_bounds__(TPB) void conv_atomic_kernel(
    const unsigned* __restrict__ PA, const unsigned* __restrict__ PE,
    unsigned* __restrict__ out)
{
    __shared__ __align__(16) unsigned eSh[EPAD];
    __shared__ __align__(16) unsigned aSh[APAD];
    const int t = (int)threadIdx.x;
    Stg S; Acc C;
    int k0, i0;
    decode_pair((int)blockIdx.x, k0, i0);
    zero_acc(C);
#pragma unroll 1
    for (int cc = 0; cc < 2; ++cc) {
        load_regs(PE, PA, k0, i0 + CHUNK * cc, t, S);
        if (cc) __syncthreads();
        dsw(eSh, aSh, t, S);
        __syncthreads();
        compute_chunk(eSh, aSh, t, C);
    }
    unsigned* o = out + k0 + 16 * t;
    atomicAdd(&o[0], C.ae0);  atomicAdd(&o[1], C.ao0);
    atomicAdd(&o[2], C.ae1);  atomicAdd(&o[3], C.ao1);
    atomicAdd(&o[4], C.ae2);  atomicAdd(&o[5], C.ao2);
    atomicAdd(&o[6], C.ae3);  atomicAdd(&o[7], C.ao3);
    atomicAdd(&o[8], C.ae4);  atomicAdd(&o[9], C.ao4);
    atomicAdd(&o[10], C.ae5); atomicAdd(&o[11], C.ao5);
    atomicAdd(&o[12], C.ae6); atomicAdd(&o[13], C.ao6);
    atomicAdd(&o[14], C.ae7); atomicAdd(&o[15], C.ao7);
}

extern "C" void kernel_launch(void* const* d_in, const int* in_sizes, int n_in,
                              void* d_out, int out_size, void* d_ws, size_t ws_size,
                              hipStream_t stream)
{
    const int* A = (const int*)d_in[0];
    const int* B = (const int*)d_in[1];
    unsigned* out = (unsigned*)d_out;
    unsigned* ws = (unsigned*)d_ws;

    const size_t need = ((size_t)P_OFS + (size_t)NPAIRS * TILE) * 4;  // ~9.6 MB
    pack_kernel<<<(NPACK + TPB - 1) / TPB, TPB, 0, stream>>>(A, B, ws);

    if (ws_size >= need) {
        hipMemsetAsync((char*)d_ws + (size_t)CTR_OFS * 4, 0, 4, stream);
        conv_kernel<<<GRID, TPB, 0, stream>>>(ws + PA_OFS, ws + PE_OFS,
                                              ws + CTR_OFS, ws + P_OFS);
        reduce_kernel<<<(2 * MM) / TPB, TPB, 0, stream>>>(ws + P_OFS, out);
    } else {
        hipMemsetAsync(d_out, 0, (size_t)out_size * sizeof(int), stream);
        conv_atomic_kernel<<<NPAIRS, TPB, 0, stream>>>(ws + PA_OFS, ws + PE_OFS, out);
    }
}

// Round 8
// 43.256 us; speedup vs baseline: 1.3817x; 1.3817x over previous
//
#include <hip/hip_runtime.h>

#define MM     32768
#define TPB    256
#define TILE   4096                // bins per tile
#define NTILE  16
#define CHUNK  256                 // i-limbs per block
#define EPAD   2208                // staged window dwords per parity (2176 live + prefetch pad)
#define APAD   144                 // A dwords (128 live + prefetch pad)
#define NBLK   1152                // (tile, chunk) blocks; also partial-slice count

typedef unsigned short ushort2e __attribute__((ext_vector_type(2)));

// 2 exact u16 MACs mod 2^32 (u32 wrap == the int32 the harness compares).
__device__ __forceinline__ unsigned DOT2(unsigned a, unsigned b, unsigned c) {
#if __has_builtin(__builtin_amdgcn_udot2)
    return __builtin_amdgcn_udot2(__builtin_bit_cast(ushort2e, a),
                                  __builtin_bit_cast(ushort2e, b), c, false);
#else
    return c + (a & 0xFFFFu) * (b & 0xFFFFu) + (a >> 16) * (b >> 16);
#endif
}

// LDS dword swizzle: XOR dword bits 5-7 into bank bits 2-4. Bijective within
// 32-dword blocks, preserves 16B quads (bits 0-1 untouched). Staging writes
// (s = t + 256j) stay conflict-free; stride-8 reads spread across all quads.
__device__ __forceinline__ int swz(int s) { return s ^ ((s >> 3) & 0x1C); }

// Chunks per tile: 16(t+1) for t<8 else 16(16-t); sum = 1152.
__device__ __forceinline__ int cnt_of(int t) {
    return (t < NTILE / 2) ? 16 * (t + 1) : 16 * (NTILE - t);
}

struct Acc { unsigned ae0,ae1,ae2,ae3,ae4,ae5,ae6,ae7,
                      ao0,ao1,ao2,ao3,ao4,ao5,ao6,ao7; };

// Row: 8 even + 8 odd dot2 sharing one broadcast A value.
#define STEP16(a, E0v,E1v,E2v,E3v,E4v,E5v,E6v,E7v,                              \
                  O0v,O1v,O2v,O3v,O4v,O5v,O6v,O7v)                              \
    C.ae0 = DOT2(a, E0v, C.ae0); C.ae1 = DOT2(a, E1v, C.ae1);                   \
    C.ae2 = DOT2(a, E2v, C.ae2); C.ae3 = DOT2(a, E3v, C.ae3);                   \
    C.ae4 = DOT2(a, E4v, C.ae4); C.ae5 = DOT2(a, E5v, C.ae5);                   \
    C.ae6 = DOT2(a, E6v, C.ae6); C.ae7 = DOT2(a, E7v, C.ae7);                   \
    C.ao0 = DOT2(a, O0v, C.ao0); C.ao1 = DOT2(a, O1v, C.ao1);                   \
    C.ao2 = DOT2(a, O2v, C.ao2); C.ao3 = DOT2(a, O3v, C.ao3);                   \
    C.ao4 = DOT2(a, O4v, C.ao4); C.ao5 = DOT2(a, O5v, C.ao5);                   \
    C.ao6 = DOT2(a, O6v, C.ao6); C.ao7 = DOT2(a, O7v, C.ao7);

// Group G (4 A-pairs j=4G..4G+3): quads G..G+2 live; prefetch quad G+3 of
// E (per-lane), O (per-lane) and A (uniform broadcast). 64 dot2 per group.
#define GROUP16(G, EW,EX,EY,EZ, OW,OX,OY,OZ, AW,AX,AY,AZ) {                     \
    EZ = *(const uint4*)&eSh[swz(bd + 4*(G) + 12)];                             \
    OZ = *(const uint4*)&oSh[swz(bd + 4*(G) + 12)];                             \
    AZ = *(const uint4*)&aSh[4*(G) + 12];                                       \
    STEP16(AW.x, EW.x,EW.y,EW.z,EW.w,EX.x,EX.y,EX.z,EX.w,                       \
           OW.x,OW.y,OW.z,OW.w,OX.x,OX.y,OX.z,OX.w)                             \
    STEP16(AW.y, EW.y,EW.z,EW.w,EX.x,EX.y,EX.z,EX.w,EY.x,                       \
           OW.y,OW.z,OW.w,OX.x,OX.y,OX.z,OX.w,OY.x)                             \
    STEP16(AW.z, EW.z,EW.w,EX.x,EX.y,EX.z,EX.w,EY.x,EY.y,                       \
           OW.z,OW.w,OX.x,OX.y,OX.z,OX.w,OY.x,OY.y)                             \
    STEP16(AW.w, EW.w,EX.x,EX.y,EX.z,EX.w,EY.x,EY.y,EY.z,                       \
           OW.w,OX.x,OX.y,OX.z,OX.w,OY.x,OY.y,OY.z)                             \
}

// Even bin k=2K: C += A2[m] dot2 E[K-m]; odd k=2K+1: dot2 O[K-m].
//   E[n] = (lo B[2n],   hi B[2n-1]),  O[n] = (lo B[2n+1], hi B[2n])
//   aSh[j] = (lo A[2m], hi A[2m+1]),  m = I0+127-j
// Thread t owns bins k0+16t+u; window dword s = 8t + j + re (re=0..7).
template <bool PARTIAL>
__global__ __launch_bounds__(TPB) void conv_kernel(
    const int* __restrict__ A, const int* __restrict__ B,
    unsigned* __restrict__ part, unsigned* __restrict__ out)
{
    __shared__ __align__(16) unsigned eSh[EPAD];
    __shared__ __align__(16) unsigned oSh[EPAD];
    __shared__ __align__(16) unsigned aSh[APAD];

    // Decode block -> (tile, chunk). Scalar loop <= 15 iters.
    int id = (int)blockIdx.x;
    int tile = 0;
#pragma unroll 1
    for (; tile < NTILE - 1; ++tile) {
        const int c = cnt_of(tile);
        if (id < c) break;
        id -= c;
    }

    const int k0 = tile << 12;
    int iMin = k0 - (MM - 1); if (iMin < 0) iMin = 0;
    const int i0 = ((iMin >> 8) + id) << 8;          // chunk base limb
    const int t  = (int)threadIdx.x;
    const int I0 = i0 >> 1;
    const int n0 = (k0 >> 1) - I0 - 127;             // window base pair index

    // Stage: pack raw B into E/O windows (zero-padded), swizzled; A uniform.
#pragma unroll
    for (int j = 0; j < 9; ++j) {
        const int s = t + 256 * j;
        if (s < EPAD) {
            const int n  = n0 + s;
            const int j0 = 2 * n, j1 = 2 * n + 1, jm = 2 * n - 1;
            const unsigned b0 = (j0 >= 0 && j0 < MM) ? (unsigned)B[j0] : 0u;
            const unsigned b1 = (j1 >= 0 && j1 < MM) ? (unsigned)B[j1] : 0u;
            const unsigned bm = (jm >= 0 && jm < MM) ? (unsigned)B[jm] : 0u;
            eSh[swz(s)] = b0 | (bm << 16);
            oSh[swz(s)] = b1 | (b0 << 16);
        }
    }
    if (t < APAD) {
        unsigned v = 0u;
        if (t < 128) {
            const int m2 = i0 + 254 - 2 * t;         // always in [0, MM-2]
            v = (unsigned)A[m2] | ((unsigned)A[m2 + 1] << 16);
        }
        aSh[t] = v;
    }
    __syncthreads();

    const int bd = 8 * t;
    Acc C;
    C.ae0=C.ae1=C.ae2=C.ae3=C.ae4=C.ae5=C.ae6=C.ae7=0u;
    C.ao0=C.ao1=C.ao2=C.ao3=C.ao4=C.ao5=C.ao6=C.ao7=0u;

    uint4 E0 = *(const uint4*)&eSh[swz(bd)];
    uint4 E1 = *(const uint4*)&eSh[swz(bd + 4)];
    uint4 E2 = *(const uint4*)&eSh[swz(bd + 8)];
    uint4 O0 = *(const uint4*)&oSh[swz(bd)];
    uint4 O1 = *(const uint4*)&oSh[swz(bd + 4)];
    uint4 O2 = *(const uint4*)&oSh[swz(bd + 8)];
    uint4 A0 = *(const uint4*)&aSh[0];
    uint4 A1 = *(const uint4*)&aSh[4];
    uint4 A2 = *(const uint4*)&aSh[8];
    uint4 E3, O3, A3;

#pragma unroll
    for (int oi = 0; oi < 8; ++oi) {   // 32 groups = 128 A-pairs = 256 limbs
        GROUP16(4*oi + 0, E0,E1,E2,E3, O0,O1,O2,O3, A0,A1,A2,A3);
        GROUP16(4*oi + 1, E1,E2,E3,E0, O1,O2,O3,O0, A1,A2,A3,A0);
        GROUP16(4*oi + 2, E2,E3,E0,E1, O2,O3,O0,O1, A2,A3,A0,A1);
        GROUP16(4*oi + 3, E3,E0,E1,E2, O3,O0,O1,O2, A3,A0,A1,A2);
    }

    if (PARTIAL) {
        unsigned* w = part + (size_t)blockIdx.x * TILE + 16 * t;
        *(uint4*)&w[0]  = make_uint4(C.ae0, C.ao0, C.ae1, C.ao1);
        *(uint4*)&w[4]  = make_uint4(C.ae2, C.ao2, C.ae3, C.ao3);
        *(uint4*)&w[8]  = make_uint4(C.ae4, C.ao4, C.ae5, C.ao5);
        *(uint4*)&w[12] = make_uint4(C.ae6, C.ao6, C.ae7, C.ao7);
    } else {
        unsigned* o = out + k0 + 16 * t;
        atomicAdd(&o[0],  C.ae0); atomicAdd(&o[1],  C.ao0);
        atomicAdd(&o[2],  C.ae1); atomicAdd(&o[3],  C.ao1);
        atomicAdd(&o[4],  C.ae2); atomicAdd(&o[5],  C.ao2);
        atomicAdd(&o[6],  C.ae3); atomicAdd(&o[7],  C.ao3);
        atomicAdd(&o[8],  C.ae4); atomicAdd(&o[9],  C.ao4);
        atomicAdd(&o[10], C.ae5); atomicAdd(&o[11], C.ao5);
        atomicAdd(&o[12], C.ae6); atomicAdd(&o[13], C.ao6);
        atomicAdd(&o[14], C.ae7); atomicAdd(&o[15], C.ao7);
    }
}

// out[k] = sum over the owning tile's partial slices (mod 2^32).
__global__ __launch_bounds__(TPB) void reduce_kernel(
    const unsigned* __restrict__ part, unsigned* __restrict__ out)
{
    const int k = (int)blockIdx.x * TPB + (int)threadIdx.x;
    const int tile = k >> 12;

    int base = 0;
#pragma unroll 1
    for (int s = 0; s < NTILE - 1; ++s) {
        if (s >= tile) break;
        base += cnt_of(s);
    }
    const int cnt = cnt_of(tile);

    const unsigned* p = part + (size_t)base * TILE + (k & (TILE - 1));
    unsigned s0 = 0, s1 = 0, s2 = 0, s3 = 0;
    int c = 0;
#pragma unroll 1
    for (; c + 4 <= cnt; c += 4) {   // independent chains pipeline the loads
        s0 += p[(size_t)(c + 0) * TILE]; s1 += p[(size_t)(c + 1) * TILE];
        s2 += p[(size_t)(c + 2) * TILE]; s3 += p[(size_t)(c + 3) * TILE];
    }
    for (; c < cnt; ++c) s0 += p[(size_t)c * TILE];
    out[k] = s0 + s1 + s2 + s3;
}

extern "C" void kernel_launch(void* const* d_in, const int* in_sizes, int n_in,
                              void* d_out, int out_size, void* d_ws, size_t ws_size,
                              hipStream_t stream)
{
    const int* A = (const int*)d_in[0];
    const int* B = (const int*)d_in[1];
    unsigned* out = (unsigned*)d_out;
    unsigned* ws = (unsigned*)d_ws;

    const size_t need = (size_t)NBLK * TILE * 4;   // 18.9 MB of partials
    if (ws_size >= need) {
        conv_kernel<true><<<NBLK, TPB, 0, stream>>>(A, B, ws, out);
        reduce_kernel<<<(2 * MM) / TPB, TPB, 0, stream>>>(ws, out);
    } else {
        hipMemsetAsync(d_out, 0, (size_t)out_size * sizeof(int), stream);
        conv_kernel<false><<<NBLK, TPB, 0, stream>>>(A, B, nullptr, out);
    }
}

// Round 9
// 34.664 us; speedup vs baseline: 1.7242x; 1.2479x over previous
//
#include <hip/hip_runtime.h>

#define MM    32768
#define OUTN  65536
#define NBC   64                  // output blocks of 1024 bins
#define NSTW  16                  // i0-steps (of 32 limbs) per work unit
#define APL   1536                // revA bytes per digit plane (1504 live, pad to x64)
#define BPL   608                 // B-phase bytes per (plane,phase) (543 live, pad)
#define BOFF  (3 * APL)           // 4608
#define LDSZ  (BOFF + 12 * BPL)   // 11904 bytes

typedef int i32x4  __attribute__((ext_vector_type(4)));
typedef int i32x16 __attribute__((ext_vector_type(16)));

// Per output block b (c0 = 1024b): i-sweep start (aligned, possibly <0) and
// number of 16-step units. Same formula on host and device.
__host__ __device__ inline void blk_params(int b, int* Istart, int* units) {
    const int c0 = b << 10;
    int iLo = c0 - (MM - 1); if (iLo < 0) iLo = 0;
    int iHi = c0 + 1023;     if (iHi > MM - 1) iHi = MM - 1;
    const int Is = (iLo - 961) & ~31;   // ensure coverage for m=31
    const int Ie = (iHi + 31) & ~31;    // ensure coverage for m=0
    const int steps = ((Ie - Is) >> 5) + 1;
    *Istart = Is;
    *units  = (steps + NSTW - 1) / NSTW;
}

// A-read swizzle: fold addr bits 6..9 into bank bits 4..5 (reads stride 32B
// across the 32 m-lanes -> spreads 16B slots over all bank groups). Preserves
// bits 0-3 -> 16B frags stay contiguous; bijective within 64B; APL % 64 == 0.
__device__ __forceinline__ int swzA(int a) {
    return a ^ ((a >> 2) & 0x30) ^ ((a >> 4) & 0x30);
}
__device__ __forceinline__ unsigned ldv(const int* __restrict__ p, int x) {
    return ((unsigned)x < (unsigned)MM) ? (unsigned)p[x] : 0u;
}
__device__ __forceinline__ unsigned pk4(unsigned b0, unsigned b1, unsigned b2, unsigned b3) {
    return b0 | (b1 << 8) | (b2 << 16) | (b3 << 24);
}
__device__ __forceinline__ i32x16 z16() {
    i32x16 v;
#pragma unroll
    for (int i = 0; i < 16; ++i) v[i] = 0;
    return v;
}

// One wave = one unit: output block c0 (1024 bins), 16 i0-steps of 32 limbs.
// Digits: limb = d0 + 128 d1 + 16384 d2 (d* in [0,127], s8-safe).
// Per step s (i0 = S0+32s), per plane pair (p,q):
//   acc[p+q][m][n] += sum_k dA_p[i0+32m-k] * dB_q[(c0-i0)+k+n]
// A staged reversed (revA[u] = dA[ATop-u]) -> aligned b128 frag reads.
// B staged as 63-byte Hankel band, replicated at 4 byte-phases -> dword reads.
template <bool PARTIAL>
__global__ __launch_bounds__(64) void conv_mfma(
    const int* __restrict__ A, const int* __restrict__ B,
    unsigned* __restrict__ part, unsigned* __restrict__ out)
{
    __shared__ __align__(16) char lds[LDSZ];

    // Decode blockIdx -> (block, unit). Scalar loop, 64 iters max.
    int id = (int)blockIdx.x, blk = 0, Istart = 0, un = 0;
#pragma unroll 1
    for (; blk < NBC; ++blk) {
        blk_params(blk, &Istart, &un);
        if (id < un) break;
        id -= un;
    }
    const int c0   = blk << 10;
    const int S0   = Istart + 512 * id;   // first i0 of this unit
    const int ATop = S0 + 1472;           // top limb of the A window
    const int JB   = c0 - S0 - 480;       // base limb of the B band
    const int l    = (int)threadIdx.x;

    // ---- Stage A: revA_p[4w+b] = digit_p(A[ATop-4w-b]), swizzled ----
#pragma unroll 1
    for (int it = 0; it < 6; ++it) {
        const int w = l + (it << 6);
        if (w < 376) {
            const int x0 = ATop - 4 * w;
            const unsigned v0 = ldv(A, x0),     v1 = ldv(A, x0 - 1);
            const unsigned v2 = ldv(A, x0 - 2), v3 = ldv(A, x0 - 3);
            const int wa = swzA(4 * w);
            *(unsigned*)&lds[0 * APL + wa] = pk4(v0 & 127, v1 & 127, v2 & 127, v3 & 127);
            *(unsigned*)&lds[1 * APL + wa] = pk4((v0 >> 7) & 127, (v1 >> 7) & 127,
                                                 (v2 >> 7) & 127, (v3 >> 7) & 127);
            *(unsigned*)&lds[2 * APL + wa] = pk4(v0 >> 14, v1 >> 14, v2 >> 14, v3 >> 14);
        }
    }

    // ---- Stage B: phase r dword w of plane q = digits of limbs JB+4w+r..+3 ----
#pragma unroll 1
    for (int it = 0; it < 3; ++it) {
        const int w = l + (it << 6);
        if (w < 144) {
            const int j = JB + 4 * w;
            const unsigned u0 = ldv(B, j),     u1 = ldv(B, j + 1), u2 = ldv(B, j + 2);
            const unsigned u3 = ldv(B, j + 3), u4 = ldv(B, j + 4), u5 = ldv(B, j + 5);
            const unsigned u6 = ldv(B, j + 6);
            const int wb = BOFF + 4 * w;
#define BPLANE(q, D0, D1, D2, D3, D4, D5, D6)                                   \
            *(unsigned*)&lds[wb + ((q)*4 + 0) * BPL] = pk4(D0, D1, D2, D3);     \
            *(unsigned*)&lds[wb + ((q)*4 + 1) * BPL] = pk4(D1, D2, D3, D4);     \
            *(unsigned*)&lds[wb + ((q)*4 + 2) * BPL] = pk4(D2, D3, D4, D5);     \
            *(unsigned*)&lds[wb + ((q)*4 + 3) * BPL] = pk4(D3, D4, D5, D6);
            BPLANE(0, u0 & 127, u1 & 127, u2 & 127, u3 & 127, u4 & 127, u5 & 127, u6 & 127)
            BPLANE(1, (u0 >> 7) & 127, (u1 >> 7) & 127, (u2 >> 7) & 127,
                      (u3 >> 7) & 127, (u4 >> 7) & 127, (u5 >> 7) & 127, (u6 >> 7) & 127)
            BPLANE(2, u0 >> 14, u1 >> 14, u2 >> 14, u3 >> 14, u4 >> 14, u5 >> 14, u6 >> 14)
#undef BPLANE
        }
    }
    __syncthreads();

    const int n = l & 31, h = l >> 5;     // n = output col, h = k-half
    const int aInv = 1472 + 16 * h - 32 * n;                         // m = n
    const int bInv = BOFF + (n & 3) * BPL + 4 * (120 + 4 * h + (n >> 2));

    i32x16 acc0 = z16(), acc1 = z16(), acc2 = z16(), acc3 = z16(), acc4 = z16();

#pragma unroll 2
    for (int s = 0; s < NSTW; ++s) {
        const int aa = swzA(aInv - 32 * s);
        const i32x4 a0 = *(const i32x4*)&lds[0 * APL + aa];
        const i32x4 a1 = *(const i32x4*)&lds[1 * APL + aa];
        const i32x4 a2 = *(const i32x4*)&lds[2 * APL + aa];
        const int bb = bInv - 32 * s;
        i32x4 b0, b1, b2;
#pragma unroll
        for (int j = 0; j < 4; ++j) {
            b0[j] = *(const int*)&lds[bb + 0 * 4 * BPL + 4 * j];
            b1[j] = *(const int*)&lds[bb + 1 * 4 * BPL + 4 * j];
            b2[j] = *(const int*)&lds[bb + 2 * 4 * BPL + 4 * j];
        }
        // 9 plane pairs, same-acc calls spread apart.
        acc0 = __builtin_amdgcn_mfma_i32_32x32x32_i8(a0, b0, acc0, 0, 0, 0);
        acc1 = __builtin_amdgcn_mfma_i32_32x32x32_i8(a0, b1, acc1, 0, 0, 0);
        acc2 = __builtin_amdgcn_mfma_i32_32x32x32_i8(a0, b2, acc2, 0, 0, 0);
        acc3 = __builtin_amdgcn_mfma_i32_32x32x32_i8(a1, b2, acc3, 0, 0, 0);
        acc4 = __builtin_amdgcn_mfma_i32_32x32x32_i8(a2, b2, acc4, 0, 0, 0);
        acc1 = __builtin_amdgcn_mfma_i32_32x32x32_i8(a1, b0, acc1, 0, 0, 0);
        acc2 = __builtin_amdgcn_mfma_i32_32x32x32_i8(a1, b1, acc2, 0, 0, 0);
        acc3 = __builtin_amdgcn_mfma_i32_32x32x32_i8(a2, b1, acc3, 0, 0, 0);
        acc2 = __builtin_amdgcn_mfma_i32_32x32x32_i8(a2, b0, acc2, 0, 0, 0);
    }

    // Epilogue: combine digit scales mod 2^32; C/D layout (verified):
    // col = lane&31, row = (r&3) + 8*(r>>2) + 4*(lane>>5).
#pragma unroll
    for (int r = 0; r < 16; ++r) {
        const unsigned v = (unsigned)acc0[r]
                         + ((unsigned)acc1[r] << 7)
                         + ((unsigned)acc2[r] << 14)
                         + ((unsigned)acc3[r] << 21)
                         + ((unsigned)acc4[r] << 28);
        const int idx = 32 * ((r & 3) + 8 * (r >> 2) + 4 * h) + n;
        if (PARTIAL) {
            part[((size_t)blockIdx.x << 10) + idx] = v;
        } else {
            atomicAdd(&out[c0 + idx], v);
        }
    }
}

// out[c] = sum over the owning block's unit slices (mod 2^32).
__global__ __launch_bounds__(256) void reduce_k(
    const unsigned* __restrict__ part, unsigned* __restrict__ out)
{
    const int c = (int)blockIdx.x * 256 + (int)threadIdx.x;
    const int blk = c >> 10;        // uniform within the 256-thread block

    int base = 0, un = 0, Is = 0;
#pragma unroll 1
    for (int b = 0; b < NBC; ++b) {
        blk_params(b, &Is, &un);
        if (b == blk) break;
        base += un;
    }

    const unsigned* p = part + ((size_t)base << 10) + (c & 1023);
    unsigned s0 = 0, s1 = 0, s2 = 0, s3 = 0;
    int i = 0;
#pragma unroll 1
    for (; i + 4 <= un; i += 4) {
        s0 += p[(size_t)(i + 0) << 10]; s1 += p[(size_t)(i + 1) << 10];
        s2 += p[(size_t)(i + 2) << 10]; s3 += p[(size_t)(i + 3) << 10];
    }
    for (; i < un; ++i) s0 += p[(size_t)i << 10];
    out[c] = s0 + s1 + s2 + s3;
}

extern "C" void kernel_launch(void* const* d_in, const int* in_sizes, int n_in,
                              void* d_out, int out_size, void* d_ws, size_t ws_size,
                              hipStream_t stream)
{
    const int* A = (const int*)d_in[0];
    const int* B = (const int*)d_in[1];
    unsigned* out = (unsigned*)d_out;
    unsigned* ws = (unsigned*)d_ws;

    int NU = 0;
    for (int b = 0; b < NBC; ++b) {
        int Is, un;
        blk_params(b, &Is, &un);
        NU += un;
    }

    const size_t need = (size_t)NU * 1024 * sizeof(unsigned);  // ~9.2 MB
    if (ws_size >= need) {
        conv_mfma<true><<<NU, 64, 0, stream>>>(A, B, ws, out);
        reduce_k<<<OUTN / 256, 256, 0, stream>>>(ws, out);
    } else {
        hipMemsetAsync(d_out, 0, (size_t)out_size * sizeof(int), stream);
        conv_mfma<false><<<NU, 64, 0, stream>>>(A, B, nullptr, out);
    }
}

// Round 10
// 33.695 us; speedup vs baseline: 1.7738x; 1.0287x over previous
//
#include <hip/hip_runtime.h>

#define MM    32768
#define OUTN  65536
#define NBC   64                  // output blocks of 1024 bins
#define NSTW  16                  // i0-steps (of 32 limbs) per workgroup
#define APL   1536                // revA bytes per digit plane (1504 live, pad)
#define BPL   608                 // B-phase bytes per (plane,phase) (543 live, pad)
#define BOFF  (3 * APL)           // 4608
#define ABSZ  (BOFF + 12 * BPL)   // 11904 bytes of A/B staging
#define LDSZ  16384               // reused as 4 x 1024-dword reduce buffer
#define TPB   256                 // 4 waves; each wave owns 4 of the 16 steps

typedef int i32x4  __attribute__((ext_vector_type(4)));
typedef int i32x16 __attribute__((ext_vector_type(16)));

// Per output block b (c0 = 1024b): i-sweep start (aligned) and 16-step units.
__host__ __device__ inline void blk_params(int b, int* Istart, int* units) {
    const int c0 = b << 10;
    int iLo = c0 - (MM - 1); if (iLo < 0) iLo = 0;
    int iHi = c0 + 1023;     if (iHi > MM - 1) iHi = MM - 1;
    const int Is = (iLo - 961) & ~31;
    const int Ie = (iHi + 31) & ~31;
    const int steps = ((Ie - Is) >> 5) + 1;
    *Istart = Is;
    *units  = (steps + NSTW - 1) / NSTW;
}

// A-read swizzle (verified R9): folds addr bits 6..9 into bank bits 4..5,
// preserves 16B fragments, bijective within 64B.
__device__ __forceinline__ int swzA(int a) {
    return a ^ ((a >> 2) & 0x30) ^ ((a >> 4) & 0x30);
}
__device__ __forceinline__ unsigned ldv(const int* __restrict__ p, int x) {
    return ((unsigned)x < (unsigned)MM) ? (unsigned)p[x] : 0u;
}
__device__ __forceinline__ unsigned pk4(unsigned b0, unsigned b1, unsigned b2, unsigned b3) {
    return b0 | (b1 << 8) | (b2 << 16) | (b3 << 24);
}
__device__ __forceinline__ i32x16 z16() {
    i32x16 v;
#pragma unroll
    for (int i = 0; i < 16; ++i) v[i] = 0;
    return v;
}

// One workgroup = one unit (1024 bins x 512 swept limbs); 4 waves split the
// 16 steps (wave w: s = w + 4j). Digits: limb = d0 + 128 d1 + 16384 d2.
// acc[p+q][m][n] += sum_k dA_p[i0+32m-k] * dB_q[(c0-i0)+k+n]; all math and
// fragment mappings identical to the R9 kernel that verified absmax 0.
template <bool PARTIAL>
__global__ __launch_bounds__(TPB, 4) void conv_mfma(
    const int* __restrict__ A, const int* __restrict__ B,
    unsigned* __restrict__ part, unsigned* __restrict__ out)
{
    __shared__ __align__(16) char lds[LDSZ];

    int id = (int)blockIdx.x, blk = 0, Istart = 0, un = 0;
#pragma unroll 1
    for (; blk < NBC; ++blk) {
        blk_params(blk, &Istart, &un);
        if (id < un) break;
        id -= un;
    }
    const int c0   = blk << 10;
    const int S0   = Istart + 512 * id;
    const int ATop = S0 + 1472;
    const int JB   = c0 - S0 - 480;
    const int l    = (int)threadIdx.x;

    // ---- Stage A (376 dwords x 3 planes; 2 iterations over 256 lanes) ----
#pragma unroll
    for (int it = 0; it < 2; ++it) {
        const int w = l + (it << 8);
        if (w < 376) {
            const int x0 = ATop - 4 * w;
            const unsigned v0 = ldv(A, x0),     v1 = ldv(A, x0 - 1);
            const unsigned v2 = ldv(A, x0 - 2), v3 = ldv(A, x0 - 3);
            const int wa = swzA(4 * w);
            *(unsigned*)&lds[0 * APL + wa] = pk4(v0 & 127, v1 & 127, v2 & 127, v3 & 127);
            *(unsigned*)&lds[1 * APL + wa] = pk4((v0 >> 7) & 127, (v1 >> 7) & 127,
                                                 (v2 >> 7) & 127, (v3 >> 7) & 127);
            *(unsigned*)&lds[2 * APL + wa] = pk4(v0 >> 14, v1 >> 14, v2 >> 14, v3 >> 14);
        }
    }

    // ---- Stage B (144 dwords x 3 planes x 4 byte-phases) ----
    if (l < 144) {
        const int j = JB + 4 * l;
        const unsigned u0 = ldv(B, j),     u1 = ldv(B, j + 1), u2 = ldv(B, j + 2);
        const unsigned u3 = ldv(B, j + 3), u4 = ldv(B, j + 4), u5 = ldv(B, j + 5);
        const unsigned u6 = ldv(B, j + 6);
        const int wb = BOFF + 4 * l;
#define BPLANE(q, D0, D1, D2, D3, D4, D5, D6)                                   \
        *(unsigned*)&lds[wb + ((q)*4 + 0) * BPL] = pk4(D0, D1, D2, D3);         \
        *(unsigned*)&lds[wb + ((q)*4 + 1) * BPL] = pk4(D1, D2, D3, D4);         \
        *(unsigned*)&lds[wb + ((q)*4 + 2) * BPL] = pk4(D2, D3, D4, D5);         \
        *(unsigned*)&lds[wb + ((q)*4 + 3) * BPL] = pk4(D3, D4, D5, D6);
        BPLANE(0, u0 & 127, u1 & 127, u2 & 127, u3 & 127, u4 & 127, u5 & 127, u6 & 127)
        BPLANE(1, (u0 >> 7) & 127, (u1 >> 7) & 127, (u2 >> 7) & 127,
                  (u3 >> 7) & 127, (u4 >> 7) & 127, (u5 >> 7) & 127, (u6 >> 7) & 127)
        BPLANE(2, u0 >> 14, u1 >> 14, u2 >> 14, u3 >> 14, u4 >> 14, u5 >> 14, u6 >> 14)
#undef BPLANE
    }
    __syncthreads();

    const int wv = l >> 6;                 // wave id 0..3
    const int ll = l & 63;
    const int n  = ll & 31, h = ll >> 5;   // output col, k-half
    const int aInv = 1472 + 16 * h - 32 * n;
    const int bInv = BOFF + (n & 3) * BPL + 4 * (120 + 4 * h + (n >> 2));

    i32x16 acc0 = z16(), acc1 = z16(), acc2 = z16(), acc3 = z16(), acc4 = z16();

#pragma unroll
    for (int j = 0; j < 4; ++j) {
        const int s = wv + 4 * j;          // this wave's 4 of the 16 steps
        const int aa = swzA(aInv - 32 * s);
        const i32x4 a0 = *(const i32x4*)&lds[0 * APL + aa];
        const i32x4 a1 = *(const i32x4*)&lds[1 * APL + aa];
        const i32x4 a2 = *(const i32x4*)&lds[2 * APL + aa];
        const int bb = bInv - 32 * s;
        i32x4 b0, b1, b2;
#pragma unroll
        for (int q = 0; q < 4; ++q) {
            b0[q] = *(const int*)&lds[bb + 0 * 4 * BPL + 4 * q];
            b1[q] = *(const int*)&lds[bb + 1 * 4 * BPL + 4 * q];
            b2[q] = *(const int*)&lds[bb + 2 * 4 * BPL + 4 * q];
        }
        acc0 = __builtin_amdgcn_mfma_i32_32x32x32_i8(a0, b0, acc0, 0, 0, 0);
        acc1 = __builtin_amdgcn_mfma_i32_32x32x32_i8(a0, b1, acc1, 0, 0, 0);
        acc2 = __builtin_amdgcn_mfma_i32_32x32x32_i8(a0, b2, acc2, 0, 0, 0);
        acc3 = __builtin_amdgcn_mfma_i32_32x32x32_i8(a1, b2, acc3, 0, 0, 0);
        acc4 = __builtin_amdgcn_mfma_i32_32x32x32_i8(a2, b2, acc4, 0, 0, 0);
        acc1 = __builtin_amdgcn_mfma_i32_32x32x32_i8(a1, b0, acc1, 0, 0, 0);
        acc2 = __builtin_amdgcn_mfma_i32_32x32x32_i8(a1, b1, acc2, 0, 0, 0);
        acc3 = __builtin_amdgcn_mfma_i32_32x32x32_i8(a2, b1, acc3, 0, 0, 0);
        acc2 = __builtin_amdgcn_mfma_i32_32x32x32_i8(a2, b0, acc2, 0, 0, 0);
    }

    // Combine digit scales mod 2^32; park per-wave partials in reused LDS.
    __syncthreads();                        // all waves done reading A/B
    unsigned* red = (unsigned*)lds;
#pragma unroll
    for (int r = 0; r < 16; ++r) {
        const unsigned v = (unsigned)acc0[r]
                         + ((unsigned)acc1[r] << 7)
                         + ((unsigned)acc2[r] << 14)
                         + ((unsigned)acc3[r] << 21)
                         + ((unsigned)acc4[r] << 28);
        const int idx = 32 * ((r & 3) + 8 * (r >> 2) + 4 * h) + n;
        red[(wv << 10) + idx] = v;
    }
    __syncthreads();

    // Cross-wave sum: lane l owns bins 4l..4l+3 (uint4 reads/stores).
    const uint4* rb = (const uint4*)lds;
    uint4 t0 = rb[l], t1 = rb[256 + l], t2 = rb[512 + l], t3 = rb[768 + l];
    const uint4 tot = make_uint4(t0.x + t1.x + t2.x + t3.x,
                                 t0.y + t1.y + t2.y + t3.y,
                                 t0.z + t1.z + t2.z + t3.z,
                                 t0.w + t1.w + t2.w + t3.w);
    if (PARTIAL) {
        *(uint4*)&part[((size_t)blockIdx.x << 10) + 4 * l] = tot;
    } else {
        unsigned* o = out + c0 + 4 * l;
        atomicAdd(&o[0], tot.x); atomicAdd(&o[1], tot.y);
        atomicAdd(&o[2], tot.z); atomicAdd(&o[3], tot.w);
    }
}

// out[c] = sum over the owning block's unit slices (mod 2^32).
__global__ __launch_bounds__(256) void reduce_k(
    const unsigned* __restrict__ part, unsigned* __restrict__ out)
{
    const int c = (int)blockIdx.x * 256 + (int)threadIdx.x;
    const int blk = c >> 10;

    int base = 0, un = 0, Is = 0;
#pragma unroll 1
    for (int b = 0; b < NBC; ++b) {
        blk_params(b, &Is, &un);
        if (b == blk) break;
        base += un;
    }

    const unsigned* p = part + ((size_t)base << 10) + (c & 1023);
    unsigned s0 = 0, s1 = 0, s2 = 0, s3 = 0;
    int i = 0;
#pragma unroll 1
    for (; i + 4 <= un; i += 4) {
        s0 += p[(size_t)(i + 0) << 10]; s1 += p[(size_t)(i + 1) << 10];
        s2 += p[(size_t)(i + 2) << 10]; s3 += p[(size_t)(i + 3) << 10];
    }
    for (; i < un; ++i) s0 += p[(size_t)i << 10];
    out[c] = s0 + s1 + s2 + s3;
}

extern "C" void kernel_launch(void* const* d_in, const int* in_sizes, int n_in,
                              void* d_out, int out_size, void* d_ws, size_t ws_size,
                              hipStream_t stream)
{
    const int* A = (const int*)d_in[0];
    const int* B = (const int*)d_in[1];
    unsigned* out = (unsigned*)d_out;
    unsigned* ws = (unsigned*)d_ws;

    int NU = 0;
    for (int b = 0; b < NBC; ++b) {
        int Is, un;
        blk_params(b, &Is, &un);
        NU += un;
    }

    const size_t need = (size_t)NU * 1024 * sizeof(unsigned);  // ~8.9 MB
    if (ws_size >= need) {
        conv_mfma<true><<<NU, TPB, 0, stream>>>(A, B, ws, out);
        reduce_k<<<OUTN / 256, 256, 0, stream>>>(ws, out);
    } else {
        hipMemsetAsync(d_out, 0, (size_t)out_size * sizeof(int), stream);
        conv_mfma<false><<<NU, TPB, 0, stream>>>(A, B, nullptr, out);
    }
}